// Round 6
// baseline (384.607 us; speedup 1.0000x reference)
//
#include <hip/hip_runtime.h>
#include <math.h>

#define M_ROWS 16384   // B*S
#define E_DIM 768
#define FFN_DIM 3072
#define NQ 8

typedef __bf16 bf16x8 __attribute__((ext_vector_type(8)));
typedef float f32x4 __attribute__((ext_vector_type(4)));
typedef unsigned short ushortx8 __attribute__((ext_vector_type(8)));
typedef unsigned short ushortx4 __attribute__((ext_vector_type(4)));
typedef unsigned short ushort;

static __device__ __forceinline__ ushort f2bf(float f) {
    unsigned u = __float_as_uint(f);
    unsigned r = (u + 0x7FFFu + ((u >> 16) & 1u)) >> 16;
    return (ushort)r;
}

static __device__ __forceinline__ bf16x8 as_bf16x8(ushortx8 v) {
    union { ushortx8 u; bf16x8 b; } x; x.u = v; return x.b;
}

// ---------------------------------------------------------------------------
// Kernel 1: A1[m,e] = bf16( cos(x[m,e] + rx[e & 63]) )
// ---------------------------------------------------------------------------
__global__ __launch_bounds__(256) void k_prep_a1(const float* __restrict__ x,
                                                 const float* __restrict__ rx,
                                                 ushort* __restrict__ a1) {
    long idx = ((long)blockIdx.x * 256 + threadIdx.x) * 4;
    float4 v = *(const float4*)(x + idx);
    int r = (int)(idx & 63);
    ushortx4 o;
    o[0] = f2bf(__cosf(v.x + rx[r + 0]));
    o[1] = f2bf(__cosf(v.y + rx[r + 1]));
    o[2] = f2bf(__cosf(v.z + rx[r + 2]));
    o[3] = f2bf(__cosf(v.w + rx[r + 3]));
    *(ushortx4*)(a1 + idx) = o;
}

// ---------------------------------------------------------------------------
// Kernel 2: LDS-tiled transpose fp32 (R x C) -> bf16 (C x R)
// ---------------------------------------------------------------------------
__global__ __launch_bounds__(256) void k_transpose_bf(const float* __restrict__ in,
                                                      ushort* __restrict__ out,
                                                      int R, int C) {
    __shared__ float tile[32][33];
    int c0 = blockIdx.x * 32, r0 = blockIdx.y * 32;
    int tx = threadIdx.x & 31, ty = threadIdx.x >> 5;
#pragma unroll
    for (int i = 0; i < 32; i += 8) {
        tile[ty + i][tx] = in[(long)(r0 + ty + i) * C + c0 + tx];
    }
    __syncthreads();
#pragma unroll
    for (int i = 0; i < 32; i += 8) {
        out[(long)(c0 + ty + i) * R + r0 + tx] = f2bf(tile[tx][ty + i]);
    }
}

// ---------------------------------------------------------------------------
// Kernel 3: bf16 MFMA GEMM, C[M,N] = A[M,K] * Bt[N,K]^T + bias[N], fp32 out.
// R5's XOR-swizzled flat [128][64] LDS tile (conflict-free both sides,
// 128B-contiguous global segments — verified R5: 0 conflicts, FETCH ~87MB)
// + software pipeline: prefetch K-tile kt+64 into VGPRs BETWEEN the
// post-stage barrier and compute(kt), so the global-load latency is hidden
// behind ~64 MFMAs. 2x unrolled (K%128==0: 768, 3072) -> no reg copies.
// ---------------------------------------------------------------------------
__global__ __launch_bounds__(256, 2)
void k_gemm_bt(const ushort* __restrict__ A, const ushort* __restrict__ Bt,
               const float* __restrict__ bias, float* __restrict__ C,
               int M, int N, int K) {
    __shared__ ushort lsA[128 * 64];
    __shared__ ushort lsB[128 * 64];
    const int tid = threadIdx.x;
    const int lane = tid & 63;
    const int wave = tid >> 6;
    const int wm = wave & 1, wn = wave >> 1;
    const long m0 = (long)blockIdx.x * 128;
    const long n0 = (long)blockIdx.y * 128;

    // staging: row = tid>>3 (+32/issue), global chunk = tid&7 (128B/8 lanes)
    const int srow = tid >> 3;
    const int swc = (tid & 7) ^ ((tid >> 3) & 7);   // swizzled LDS chunk
    const ushort* gA = A + (m0 + srow) * (long)K + (tid & 7) * 8;
    const ushort* gB = Bt + (n0 + srow) * (long)K + (tid & 7) * 8;
    ushort* wA = lsA + srow * 64 + swc * 8;         // + i*2048 per issue
    ushort* wB = lsB + srow * 64 + swc * 8;

    f32x4 acc[4][4] = {};
    ushortx8 pa[4], pb[4], qa[4], qb[4];

    const int rbase = lane & 15;
    const int khalf = lane >> 4;   // 0..3
    const int rswz = lane & 7;

#define PREFETCH(da, db, koff)                                              \
    _Pragma("unroll")                                                       \
    for (int i = 0; i < 4; ++i) {                                           \
        da[i] = *(const ushortx8*)(gA + (koff) + (long)(32 * i) * K);       \
        db[i] = *(const ushortx8*)(gB + (koff) + (long)(32 * i) * K);       \
    }

#define STAGE(sa, sb)                                                       \
    _Pragma("unroll")                                                       \
    for (int i = 0; i < 4; ++i) {                                           \
        *(ushortx8*)(wA + i * 2048) = sa[i];                                \
        *(ushortx8*)(wB + i * 2048) = sb[i];                                \
    }

#define COMPUTE()                                                                         \
    _Pragma("unroll")                                                                     \
    for (int kk = 0; kk < 64; kk += 32) {                                                 \
        const int ko = (((kk >> 3) + khalf) ^ rswz) * 8;                                  \
        bf16x8 af[4], bfr[4];                                                             \
        _Pragma("unroll")                                                                 \
        for (int t = 0; t < 4; ++t) {                                                     \
            af[t]  = as_bf16x8(*(const ushortx8*)&lsA[(wm * 64 + t * 16 + rbase) * 64 + ko]); \
            bfr[t] = as_bf16x8(*(const ushortx8*)&lsB[(wn * 64 + t * 16 + rbase) * 64 + ko]); \
        }                                                                                 \
        _Pragma("unroll")                                                                 \
        for (int tm = 0; tm < 4; ++tm)                                                    \
            _Pragma("unroll")                                                             \
            for (int tn = 0; tn < 4; ++tn)                                                \
                acc[tm][tn] = __builtin_amdgcn_mfma_f32_16x16x32_bf16(af[tm], bfr[tn], acc[tm][tn], 0, 0, 0); \
    }

    PREFETCH(pa, pb, 0)
    for (int kt = 0; kt < K; kt += 128) {
        if (kt) __syncthreads();          // consumers of tile kt-64 done
        STAGE(pa, pb)
        __syncthreads();                  // tile kt visible
        PREFETCH(qa, qb, kt + 64)         // in flight during compute(kt)
        COMPUTE()
        __syncthreads();                  // consumers of tile kt done
        STAGE(qa, qb)
        __syncthreads();                  // tile kt+64 visible
        if (kt + 128 < K) { PREFETCH(pa, pb, kt + 128) }
        COMPUTE()
    }
#undef PREFETCH
#undef STAGE
#undef COMPUTE

    // epilogue: C/D layout col = lane&15, row = (lane>>4)*4 + j  [m89/m91]
    const int cr = (lane >> 4) * 4;
    const int cc = lane & 15;
#pragma unroll
    for (int tm = 0; tm < 4; ++tm) {
#pragma unroll
        for (int tn = 0; tn < 4; ++tn) {
            long col = n0 + wn * 64 + tn * 16 + cc;
            float bb = bias[col];
#pragma unroll
            for (int j = 0; j < 4; ++j) {
                long row = m0 + wm * 64 + tm * 16 + cr + j;
                C[row * N + col] = acc[tm][tn][j] + bb;
            }
        }
    }
}

// ---------------------------------------------------------------------------
// Kernel 4: fused residual + LayerNorm, one WAVE per row (no barriers).
// Optional q = cos(x1[:, :8]) * cos(ry) for the FFN path.
// ---------------------------------------------------------------------------
__global__ __launch_bounds__(256) void k_ln(const float* __restrict__ x,
                                            const float* __restrict__ y,
                                            const float* __restrict__ g,
                                            const float* __restrict__ b,
                                            float* __restrict__ out,
                                            float* __restrict__ qout,
                                            const float* __restrict__ ry,
                                            int withq) {
    const int lane = threadIdx.x & 63;
    const int wave = threadIdx.x >> 6;
    const long row = (long)blockIdx.x * 4 + wave;
    const float* xr = x + row * E_DIM;
    const float* yr = y + row * E_DIM;
    float4 v[3];
    float s = 0.f, ss = 0.f;
#pragma unroll
    for (int i = 0; i < 3; ++i) {
        int c = lane * 4 + i * 256;
        float4 a = *(const float4*)(xr + c);
        float4 d = *(const float4*)(yr + c);
        v[i].x = a.x + d.x; v[i].y = a.y + d.y;
        v[i].z = a.z + d.z; v[i].w = a.w + d.w;
        s  += v[i].x + v[i].y + v[i].z + v[i].w;
        ss += v[i].x * v[i].x + v[i].y * v[i].y + v[i].z * v[i].z + v[i].w * v[i].w;
    }
#pragma unroll
    for (int o = 1; o < 64; o <<= 1) {
        s  += __shfl_xor(s, o);
        ss += __shfl_xor(ss, o);
    }
    const float mu = s * (1.f / E_DIM);
    const float rstd = rsqrtf(ss * (1.f / E_DIM) - mu * mu + 1e-5f);
#pragma unroll
    for (int i = 0; i < 3; ++i) {
        int c = lane * 4 + i * 256;
        float4 gg = *(const float4*)(g + c);
        float4 bb = *(const float4*)(b + c);
        float4 o;
        o.x = (v[i].x - mu) * rstd * gg.x + bb.x;
        o.y = (v[i].y - mu) * rstd * gg.y + bb.y;
        o.z = (v[i].z - mu) * rstd * gg.z + bb.z;
        o.w = (v[i].w - mu) * rstd * gg.w + bb.w;
        *(float4*)(out + row * E_DIM + c) = o;
        if (withq && i == 0 && lane < 2) {
            float4 r4 = *(const float4*)(ry + lane * 4);
            float* qo = qout + row * NQ + lane * 4;
            qo[0] = __cosf(o.x) * __cosf(r4.x);
            qo[1] = __cosf(o.y) * __cosf(r4.y);
            qo[2] = __cosf(o.z) * __cosf(r4.z);
            qo[3] = __cosf(o.w) * __cosf(r4.w);
        }
    }
}

// ---------------------------------------------------------------------------
// Kernel 5: h[m,n] = relu(b1[n] + sum_{j<8} q[m,j]*W1[j,n]), bf16 out.
// ---------------------------------------------------------------------------
__global__ __launch_bounds__(256) void k_ffn1(const float* __restrict__ q,
                                              const float* __restrict__ W1,
                                              const float* __restrict__ b1,
                                              ushort* __restrict__ h) {
    __shared__ float qs[32][NQ];
    const int r0 = blockIdx.x * 32;
    const int tid = threadIdx.x;
    qs[tid >> 3][tid & 7] = q[(long)r0 * NQ + tid];
    __syncthreads();
#pragma unroll 4
    for (int nb = 0; nb < 12; ++nb) {
        int n = nb * 256 + tid;
        float w[NQ];
#pragma unroll
        for (int j = 0; j < NQ; ++j) w[j] = W1[j * FFN_DIM + n];
        float bb = b1[n];
#pragma unroll
        for (int r = 0; r < 32; ++r) {
            float a = bb;
#pragma unroll
            for (int j = 0; j < NQ; ++j) a += qs[r][j] * w[j];
            a = a > 0.f ? a : 0.f;
            h[(long)(r0 + r) * FFN_DIM + n] = f2bf(a);
        }
    }
}

// ---------------------------------------------------------------------------

extern "C" void kernel_launch(void* const* d_in, const int* in_sizes, int n_in,
                              void* d_out, int out_size, void* d_ws, size_t ws_size,
                              hipStream_t stream) {
    const float* x   = (const float*)d_in[0];
    const float* rx  = (const float*)d_in[1];
    const float* ry  = (const float*)d_in[2];
    const float* Wc  = (const float*)d_in[3];
    const float* bc  = (const float*)d_in[4];
    const float* W1  = (const float*)d_in[5];
    const float* b1  = (const float*)d_in[6];
    const float* W2  = (const float*)d_in[7];
    const float* b2  = (const float*)d_in[8];
    const float* g1  = (const float*)d_in[9];
    const float* be1 = (const float*)d_in[10];
    const float* g2  = (const float*)d_in[11];
    const float* be2 = (const float*)d_in[12];
    float* out = (float*)d_out;

    char* ws = (char*)d_ws;
    ushort* a1   = (ushort*)ws;                 ws += (size_t)M_ROWS * E_DIM * 2;
    ushort* wcT  = (ushort*)ws;                 ws += (size_t)E_DIM * E_DIM * 2;
    float*  attn = (float*)ws;                  ws += (size_t)M_ROWS * E_DIM * 4;   // reused as ffn_out
    float*  x1   = (float*)ws;                  ws += (size_t)M_ROWS * E_DIM * 4;
    float*  q    = (float*)ws;                  ws += (size_t)M_ROWS * NQ * 4;
    ushort* w2T  = (ushort*)ws;                 ws += (size_t)FFN_DIM * E_DIM * 2;
    ushort* h    = (ushort*)ws;                 ws += (size_t)M_ROWS * FFN_DIM * 2;

    // 1. A1 = bf16(cos(x + rx))
    k_prep_a1<<<(M_ROWS * E_DIM) / (256 * 4), 256, 0, stream>>>(x, rx, a1);
    // 2. WcT[n,k] = bf16(Wc[k,n]);  W2T[n,k] = bf16(W2[k,n])
    k_transpose_bf<<<dim3(E_DIM / 32, E_DIM / 32), 256, 0, stream>>>(Wc, wcT, E_DIM, E_DIM);
    k_transpose_bf<<<dim3(E_DIM / 32, FFN_DIM / 32), 256, 0, stream>>>(W2, w2T, FFN_DIM, E_DIM);
    // 3. attn = A1 @ Wc + bc
    k_gemm_bt<<<dim3(M_ROWS / 128, E_DIM / 128), 256, 0, stream>>>(a1, wcT, bc, attn, M_ROWS, E_DIM, E_DIM);
    // 4. x1 = LN(x + attn); q = cos(x1[:, :8]) * cos(ry)
    k_ln<<<M_ROWS / 4, 256, 0, stream>>>(x, attn, g1, be1, x1, q, ry, 1);
    // 5. h = relu(q @ W1 + b1)  (bf16)
    k_ffn1<<<M_ROWS / 32, 256, 0, stream>>>(q, W1, b1, h);
    // 6. ffn = h @ W2 + b2  (reuse attn buffer)
    k_gemm_bt<<<dim3(M_ROWS / 128, E_DIM / 128), 256, 0, stream>>>(h, w2T, b2, attn, M_ROWS, E_DIM, FFN_DIM);
    // 7. out = LN(x1 + ffn)
    k_ln<<<M_ROWS / 4, 256, 0, stream>>>(x1, attn, g2, be2, out, nullptr, nullptr, 0);
}

// Round 7
// 296.661 us; speedup vs baseline: 1.2965x; 1.2965x over previous
//
#include <hip/hip_runtime.h>
#include <hip/hip_fp8.h>
#include <math.h>

#define M_ROWS 16384   // B*S
#define E_DIM 768
#define FFN_DIM 3072
#define NQ 8

// h stored as fp8*16, W2^T as fp8*32; GEMM3 epilogue multiplies by 1/512.
#define HSCALE 16.0f
#define WSCALE 32.0f
#define INV_SCALE (1.0f / (16.0f * 32.0f))

typedef __bf16 bf16x8 __attribute__((ext_vector_type(8)));
typedef float f32x4 __attribute__((ext_vector_type(4)));
typedef unsigned short ushortx8 __attribute__((ext_vector_type(8)));
typedef unsigned short ushortx4 __attribute__((ext_vector_type(4)));
typedef unsigned short ushort;
typedef unsigned char uchar;

static __device__ __forceinline__ ushort f2bf(float f) {
    unsigned u = __float_as_uint(f);
    unsigned r = (u + 0x7FFFu + ((u >> 16) & 1u)) >> 16;
    return (ushort)r;
}
static __device__ __forceinline__ float bf2f(ushort u) {
    return __uint_as_float(((unsigned)u) << 16);
}
static __device__ __forceinline__ uchar f2fp8(float f) {
    return (uchar)__hip_cvt_float_to_fp8(f, __HIP_SATFINITE, __HIP_E4M3);
}
static __device__ __forceinline__ bf16x8 as_bf16x8(ushortx8 v) {
    union { ushortx8 u; bf16x8 b; } x; x.u = v; return x.b;
}

// ---------------------------------------------------------------------------
// Kernel 1: A1[m,e] = bf16( cos(x[m,e] + rx[e & 63]) )
// ---------------------------------------------------------------------------
__global__ __launch_bounds__(256) void k_prep_a1(const float* __restrict__ x,
                                                 const float* __restrict__ rx,
                                                 ushort* __restrict__ a1) {
    long idx = ((long)blockIdx.x * 256 + threadIdx.x) * 4;
    float4 v = *(const float4*)(x + idx);
    int r = (int)(idx & 63);
    ushortx4 o;
    o[0] = f2bf(__cosf(v.x + rx[r + 0]));
    o[1] = f2bf(__cosf(v.y + rx[r + 1]));
    o[2] = f2bf(__cosf(v.z + rx[r + 2]));
    o[3] = f2bf(__cosf(v.w + rx[r + 3]));
    *(ushortx4*)(a1 + idx) = o;
}

// ---------------------------------------------------------------------------
// Kernel 2a: transpose fp32 (R x C) -> bf16 (C x R)
// ---------------------------------------------------------------------------
__global__ __launch_bounds__(256) void k_transpose_bf(const float* __restrict__ in,
                                                      ushort* __restrict__ out,
                                                      int R, int C) {
    __shared__ float tile[32][33];
    int c0 = blockIdx.x * 32, r0 = blockIdx.y * 32;
    int tx = threadIdx.x & 31, ty = threadIdx.x >> 5;
#pragma unroll
    for (int i = 0; i < 32; i += 8)
        tile[ty + i][tx] = in[(long)(r0 + ty + i) * C + c0 + tx];
    __syncthreads();
#pragma unroll
    for (int i = 0; i < 32; i += 8)
        out[(long)(c0 + ty + i) * R + r0 + tx] = f2bf(tile[tx][ty + i]);
}

// ---------------------------------------------------------------------------
// Kernel 2b: transpose fp32 (R x C) -> fp8 e4m3 (C x R), scaled by WSCALE
// ---------------------------------------------------------------------------
__global__ __launch_bounds__(256) void k_transpose_fp8(const float* __restrict__ in,
                                                       uchar* __restrict__ out,
                                                       int R, int C) {
    __shared__ float tile[32][33];
    int c0 = blockIdx.x * 32, r0 = blockIdx.y * 32;
    int tx = threadIdx.x & 31, ty = threadIdx.x >> 5;
#pragma unroll
    for (int i = 0; i < 32; i += 8)
        tile[ty + i][tx] = in[(long)(r0 + ty + i) * C + c0 + tx];
    __syncthreads();
#pragma unroll
    for (int i = 0; i < 32; i += 8)
        out[(long)(c0 + ty + i) * R + r0 + tx] = f2fp8(tile[tx][ty + i] * WSCALE);
}

// ---------------------------------------------------------------------------
// Kernel 3: bf16 MFMA GEMM (R5 structure EXACTLY — proven best: VGPR 64,
// 0 conflicts, implicit wave overlap). Output stored bf16 now.
// ---------------------------------------------------------------------------
__global__ __launch_bounds__(256, 2)
void k_gemm_bt(const ushort* __restrict__ A, const ushort* __restrict__ Bt,
               const float* __restrict__ bias, ushort* __restrict__ C,
               int M, int N, int K) {
    __shared__ ushort lsA[128 * 64];
    __shared__ ushort lsB[128 * 64];
    const int tid = threadIdx.x;
    const int lane = tid & 63;
    const int wave = tid >> 6;
    const int wm = wave & 1, wn = wave >> 1;
    const long m0 = (long)blockIdx.x * 128;
    const long n0 = (long)blockIdx.y * 128;

    const int srow = tid >> 3;
    const int swc = (tid & 7) ^ ((tid >> 3) & 7);
    const ushort* gA = A + (m0 + srow) * (long)K + (tid & 7) * 8;
    const ushort* gB = Bt + (n0 + srow) * (long)K + (tid & 7) * 8;
    ushort* wA = lsA + srow * 64 + swc * 8;
    ushort* wB = lsB + srow * 64 + swc * 8;

    f32x4 acc[4][4] = {};
    const int rbase = lane & 15;
    const int khalf = lane >> 4;
    const int rswz = lane & 7;

    for (int kt = 0; kt < K; kt += 64) {
        ushortx8 av[4], bv[4];
#pragma unroll
        for (int i = 0; i < 4; ++i) {
            av[i] = *(const ushortx8*)(gA + kt + (long)(32 * i) * K);
            bv[i] = *(const ushortx8*)(gB + kt + (long)(32 * i) * K);
        }
        if (kt) __syncthreads();
#pragma unroll
        for (int i = 0; i < 4; ++i) {
            *(ushortx8*)(wA + i * 2048) = av[i];
            *(ushortx8*)(wB + i * 2048) = bv[i];
        }
        __syncthreads();
#pragma unroll
        for (int kk = 0; kk < 64; kk += 32) {
            const int ko = (((kk >> 3) + khalf) ^ rswz) * 8;
            bf16x8 af[4], bfr[4];
#pragma unroll
            for (int t = 0; t < 4; ++t) {
                af[t]  = as_bf16x8(*(const ushortx8*)&lsA[(wm * 64 + t * 16 + rbase) * 64 + ko]);
                bfr[t] = as_bf16x8(*(const ushortx8*)&lsB[(wn * 64 + t * 16 + rbase) * 64 + ko]);
            }
#pragma unroll
            for (int tm = 0; tm < 4; ++tm)
#pragma unroll
                for (int tn = 0; tn < 4; ++tn)
                    acc[tm][tn] = __builtin_amdgcn_mfma_f32_16x16x32_bf16(af[tm], bfr[tn], acc[tm][tn], 0, 0, 0);
        }
    }

    const int cr = (lane >> 4) * 4;
    const int cc = lane & 15;
#pragma unroll
    for (int tm = 0; tm < 4; ++tm)
#pragma unroll
        for (int tn = 0; tn < 4; ++tn) {
            long col = n0 + wn * 64 + tn * 16 + cc;
            float bb = bias[col];
#pragma unroll
            for (int j = 0; j < 4; ++j) {
                long row = m0 + wm * 64 + tm * 16 + cr + j;
                C[row * N + col] = f2bf(acc[tm][tn][j] + bb);
            }
        }
}

// ---------------------------------------------------------------------------
// Kernel 3b: fp8 MFMA GEMM, C[M,N] = (A8[M,K] * Bt8[N,K]^T)*INV_SCALE + bias.
// Same R5 flow/swizzle adapted to 128-byte fp8 rows (BK=128 elems):
//   staging: row=tid>>3 (+32/issue), 16B chunk (tid&7)^((tid>>3)&7)
//   frag:    s=(kk>>3)+khalf; byte off = row*128 + ((s>>1)^(row&7))*16 + (s&1)*8
//   ds_read_b64; 2-way bank aliasing only (free, m136).
// MFMA: f32_16x16x32_fp8_fp8, A/B = 8 fp8 per lane (i64 operand),
// lane layout assumed A[m=lane&15][k=(lane>>4)*8+j] (same as bf16 K=32).
// ---------------------------------------------------------------------------
__global__ __launch_bounds__(256, 2)
void k_gemm_fp8(const uchar* __restrict__ A, const uchar* __restrict__ Bt,
                const float* __restrict__ bias, ushort* __restrict__ C,
                int M, int N, int K) {
    __shared__ uchar lsA[128 * 128];
    __shared__ uchar lsB[128 * 128];
    const int tid = threadIdx.x;
    const int lane = tid & 63;
    const int wave = tid >> 6;
    const int wm = wave & 1, wn = wave >> 1;
    const long m0 = (long)blockIdx.x * 128;
    const long n0 = (long)blockIdx.y * 128;

    const int srow = tid >> 3;
    const int swc = (tid & 7) ^ ((tid >> 3) & 7);
    const uchar* gA = A + (m0 + srow) * (long)K + (tid & 7) * 16;
    const uchar* gB = Bt + (n0 + srow) * (long)K + (tid & 7) * 16;
    uchar* wA = lsA + srow * 128 + swc * 16;
    uchar* wB = lsB + srow * 128 + swc * 16;

    f32x4 acc[4][4] = {};
    const int rbase = lane & 15;
    const int khalf = lane >> 4;   // 0..3

    for (int kt = 0; kt < K; kt += 128) {
        ushortx8 av[4], bv[4];
#pragma unroll
        for (int i = 0; i < 4; ++i) {
            av[i] = *(const ushortx8*)(gA + kt + (long)(32 * i) * K);
            bv[i] = *(const ushortx8*)(gB + kt + (long)(32 * i) * K);
        }
        if (kt) __syncthreads();
#pragma unroll
        for (int i = 0; i < 4; ++i) {
            *(ushortx8*)(wA + i * 4096) = av[i];
            *(ushortx8*)(wB + i * 4096) = bv[i];
        }
        __syncthreads();
#pragma unroll
        for (int kk = 0; kk < 128; kk += 32) {
            const int s = (kk >> 3) + khalf;
            const int coff = ((s >> 1) ^ 99) * 0;  // (placeholder avoided below)
            long af[4], bfr[4];
#pragma unroll
            for (int t = 0; t < 4; ++t) {
                int rowA = wm * 64 + t * 16 + rbase;
                int rowB = wn * 64 + t * 16 + rbase;
                af[t]  = *(const long*)&lsA[rowA * 128 + (((s >> 1) ^ (rowA & 7)) * 16 + (s & 1) * 8)];
                bfr[t] = *(const long*)&lsB[rowB * 128 + (((s >> 1) ^ (rowB & 7)) * 16 + (s & 1) * 8)];
            }
            (void)coff;
#pragma unroll
            for (int tm = 0; tm < 4; ++tm)
#pragma unroll
                for (int tn = 0; tn < 4; ++tn)
                    acc[tm][tn] = __builtin_amdgcn_mfma_f32_16x16x32_fp8_fp8(af[tm], bfr[tn], acc[tm][tn], 0, 0, 0);
        }
    }

    const int cr = (lane >> 4) * 4;
    const int cc = lane & 15;
#pragma unroll
    for (int tm = 0; tm < 4; ++tm)
#pragma unroll
        for (int tn = 0; tn < 4; ++tn) {
            long col = n0 + wn * 64 + tn * 16 + cc;
            float bb = bias[col];
#pragma unroll
            for (int j = 0; j < 4; ++j) {
                long row = m0 + wm * 64 + tm * 16 + cr + j;
                C[row * N + col] = f2bf(acc[tm][tn][j] * INV_SCALE + bb);
            }
        }
}

// ---------------------------------------------------------------------------
// Kernel 4: fused residual + LayerNorm, one WAVE per row. x fp32, y bf16.
// Optional q = cos(x1[:, :8]) * cos(ry).
// ---------------------------------------------------------------------------
__global__ __launch_bounds__(256) void k_ln(const float* __restrict__ x,
                                            const ushort* __restrict__ y,
                                            const float* __restrict__ g,
                                            const float* __restrict__ b,
                                            float* __restrict__ out,
                                            float* __restrict__ qout,
                                            const float* __restrict__ ry,
                                            int withq) {
    const int lane = threadIdx.x & 63;
    const int wave = threadIdx.x >> 6;
    const long row = (long)blockIdx.x * 4 + wave;
    const float* xr = x + row * E_DIM;
    const ushort* yr = y + row * E_DIM;
    float4 v[3];
    float s = 0.f, ss = 0.f;
#pragma unroll
    for (int i = 0; i < 3; ++i) {
        int c = lane * 4 + i * 256;
        float4 a = *(const float4*)(xr + c);
        ushortx4 d4 = *(const ushortx4*)(yr + c);
        v[i].x = a.x + bf2f(d4[0]); v[i].y = a.y + bf2f(d4[1]);
        v[i].z = a.z + bf2f(d4[2]); v[i].w = a.w + bf2f(d4[3]);
        s  += v[i].x + v[i].y + v[i].z + v[i].w;
        ss += v[i].x * v[i].x + v[i].y * v[i].y + v[i].z * v[i].z + v[i].w * v[i].w;
    }
#pragma unroll
    for (int o = 1; o < 64; o <<= 1) {
        s  += __shfl_xor(s, o);
        ss += __shfl_xor(ss, o);
    }
    const float mu = s * (1.f / E_DIM);
    const float rstd = rsqrtf(ss * (1.f / E_DIM) - mu * mu + 1e-5f);
#pragma unroll
    for (int i = 0; i < 3; ++i) {
        int c = lane * 4 + i * 256;
        float4 gg = *(const float4*)(g + c);
        float4 bb = *(const float4*)(b + c);
        float4 o;
        o.x = (v[i].x - mu) * rstd * gg.x + bb.x;
        o.y = (v[i].y - mu) * rstd * gg.y + bb.y;
        o.z = (v[i].z - mu) * rstd * gg.z + bb.z;
        o.w = (v[i].w - mu) * rstd * gg.w + bb.w;
        *(float4*)(out + row * E_DIM + c) = o;
        if (withq && i == 0 && lane < 2) {
            float4 r4 = *(const float4*)(ry + lane * 4);
            float* qo = qout + row * NQ + lane * 4;
            qo[0] = __cosf(o.x) * __cosf(r4.x);
            qo[1] = __cosf(o.y) * __cosf(r4.y);
            qo[2] = __cosf(o.z) * __cosf(r4.z);
            qo[3] = __cosf(o.w) * __cosf(r4.w);
        }
    }
}

// ---------------------------------------------------------------------------
// Kernel 5: h8[m,n] = fp8( HSCALE * relu(b1[n] + sum_{j<8} q[m,j]*W1[j,n]) )
// uchar4 packed stores (256 B / wave).
// ---------------------------------------------------------------------------
__global__ __launch_bounds__(256) void k_ffn1(const float* __restrict__ q,
                                              const float* __restrict__ W1,
                                              const float* __restrict__ b1,
                                              uchar* __restrict__ h) {
    __shared__ float qs[32][NQ];
    const int r0 = blockIdx.x * 32;
    const int tid = threadIdx.x;
    qs[tid >> 3][tid & 7] = q[(long)r0 * NQ + tid];
    __syncthreads();
#pragma unroll
    for (int nb = 0; nb < 3; ++nb) {
        int n = (nb * 256 + tid) * 4;
        float4 w[NQ];
#pragma unroll
        for (int j = 0; j < NQ; ++j) w[j] = *(const float4*)(W1 + j * FFN_DIM + n);
        float4 bb = *(const float4*)(b1 + n);
#pragma unroll
        for (int r = 0; r < 32; ++r) {
            float a0 = bb.x, a1 = bb.y, a2 = bb.z, a3 = bb.w;
#pragma unroll
            for (int j = 0; j < NQ; ++j) {
                float qv = qs[r][j];
                a0 += qv * w[j].x; a1 += qv * w[j].y;
                a2 += qv * w[j].z; a3 += qv * w[j].w;
            }
            a0 = fmaxf(a0, 0.f) * HSCALE; a1 = fmaxf(a1, 0.f) * HSCALE;
            a2 = fmaxf(a2, 0.f) * HSCALE; a3 = fmaxf(a3, 0.f) * HSCALE;
            uchar4 o;
            o.x = f2fp8(a0); o.y = f2fp8(a1); o.z = f2fp8(a2); o.w = f2fp8(a3);
            *(uchar4*)(h + (long)(r0 + r) * FFN_DIM + n) = o;
        }
    }
}

// ---------------------------------------------------------------------------

extern "C" void kernel_launch(void* const* d_in, const int* in_sizes, int n_in,
                              void* d_out, int out_size, void* d_ws, size_t ws_size,
                              hipStream_t stream) {
    const float* x   = (const float*)d_in[0];
    const float* rx  = (const float*)d_in[1];
    const float* ry  = (const float*)d_in[2];
    const float* Wc  = (const float*)d_in[3];
    const float* bc  = (const float*)d_in[4];
    const float* W1  = (const float*)d_in[5];
    const float* b1  = (const float*)d_in[6];
    const float* W2  = (const float*)d_in[7];
    const float* b2  = (const float*)d_in[8];
    const float* g1  = (const float*)d_in[9];
    const float* be1 = (const float*)d_in[10];
    const float* g2  = (const float*)d_in[11];
    const float* be2 = (const float*)d_in[12];
    float* out = (float*)d_out;

    char* ws = (char*)d_ws;
    ushort* a1   = (ushort*)ws;                 ws += (size_t)M_ROWS * E_DIM * 2;     // 25 MB
    ushort* wcT  = (ushort*)ws;                 ws += (size_t)E_DIM * E_DIM * 2;      // 1.2 MB
    ushort* attn = (ushort*)ws;                 ws += (size_t)M_ROWS * E_DIM * 2;     // 25 MB (bf16, reused as ffn_out)
    float*  x1   = (float*)ws;                  ws += (size_t)M_ROWS * E_DIM * 4;     // 50 MB
    float*  q    = (float*)ws;                  ws += (size_t)M_ROWS * NQ * 4;        // 0.5 MB
    uchar*  w2T8 = (uchar*)ws;                  ws += (size_t)E_DIM * FFN_DIM;        // 2.4 MB
    uchar*  h8   = (uchar*)ws;                  ws += (size_t)M_ROWS * FFN_DIM;       // 50 MB

    // 1. A1 = bf16(cos(x + rx))
    k_prep_a1<<<(M_ROWS * E_DIM) / (256 * 4), 256, 0, stream>>>(x, rx, a1);
    // 2. WcT = bf16(Wc^T);  W2T8 = fp8(W2^T * 32)
    k_transpose_bf<<<dim3(E_DIM / 32, E_DIM / 32), 256, 0, stream>>>(Wc, wcT, E_DIM, E_DIM);
    k_transpose_fp8<<<dim3(E_DIM / 32, FFN_DIM / 32), 256, 0, stream>>>(W2, w2T8, FFN_DIM, E_DIM);
    // 3. attn(bf16) = A1 @ Wc + bc
    k_gemm_bt<<<dim3(M_ROWS / 128, E_DIM / 128), 256, 0, stream>>>(a1, wcT, bc, attn, M_ROWS, E_DIM, E_DIM);
    // 4. x1 = LN(x + attn); q = cos(x1[:, :8]) * cos(ry)
    k_ln<<<M_ROWS / 4, 256, 0, stream>>>(x, attn, g1, be1, x1, q, ry, 1);
    // 5. h8 = fp8(16 * relu(q @ W1 + b1))
    k_ffn1<<<M_ROWS / 32, 256, 0, stream>>>(q, W1, b1, h8);
    // 6. ffn(bf16) = (h8 @ W2T8)/512 + b2  (reuse attn buffer)
    k_gemm_fp8<<<dim3(M_ROWS / 128, E_DIM / 128), 256, 0, stream>>>(h8, w2T8, b2, attn, M_ROWS, E_DIM, FFN_DIM);
    // 7. out = LN(x1 + ffn)
    k_ln<<<M_ROWS / 4, 256, 0, stream>>>(x1, attn, g2, be2, out, nullptr, nullptr, 0);
}

// Round 8
// 281.238 us; speedup vs baseline: 1.3675x; 1.0548x over previous
//
#include <hip/hip_runtime.h>
#include <hip/hip_fp8.h>
#include <math.h>

#define M_ROWS 16384   // B*S
#define E_DIM 768
#define FFN_DIM 3072
#define NQ 8

// h stored as fp8*16, W2^T as fp8*32; GEMM3 epilogue multiplies by 1/512.
#define HSCALE 16.0f
#define WSCALE 32.0f
#define INV_SCALE (1.0f / (16.0f * 32.0f))

typedef __bf16 bf16x8 __attribute__((ext_vector_type(8)));
typedef float f32x4 __attribute__((ext_vector_type(4)));
typedef unsigned short ushortx8 __attribute__((ext_vector_type(8)));
typedef unsigned short ushortx4 __attribute__((ext_vector_type(4)));
typedef long longx2 __attribute__((ext_vector_type(2)));
typedef unsigned short ushort;
typedef unsigned char uchar;

static __device__ __forceinline__ ushort f2bf(float f) {
    unsigned u = __float_as_uint(f);
    unsigned r = (u + 0x7FFFu + ((u >> 16) & 1u)) >> 16;
    return (ushort)r;
}
static __device__ __forceinline__ float bf2f(ushort u) {
    return __uint_as_float(((unsigned)u) << 16);
}
static __device__ __forceinline__ uchar f2fp8(float f) {
    return (uchar)__hip_cvt_float_to_fp8(f, __HIP_SATFINITE, __HIP_E4M3);
}
static __device__ __forceinline__ bf16x8 as_bf16x8(ushortx8 v) {
    union { ushortx8 u; bf16x8 b; } x; x.u = v; return x.b;
}
// k-slice transpose within a 128-elem block: slice s (8 elems) -> position
// perm(s) = (s&3)*4 + (s>>2). Self-inverse.
static __device__ __forceinline__ int permcol(int k) {
    int q = (k >> 3) & 15;
    return (k & ~127) | ((((q & 3) << 2) | (q >> 2)) << 3) | (k & 7);
}

// ---------------------------------------------------------------------------
// Kernel 1: transpose fp32 (R x C) -> bf16 (C x R)   [for Wc]
// ---------------------------------------------------------------------------
__global__ __launch_bounds__(256) void k_transpose_bf(const float* __restrict__ in,
                                                      ushort* __restrict__ out,
                                                      int R, int C) {
    __shared__ float tile[32][33];
    int c0 = blockIdx.x * 32, r0 = blockIdx.y * 32;
    int tx = threadIdx.x & 31, ty = threadIdx.x >> 5;
#pragma unroll
    for (int i = 0; i < 32; i += 8)
        tile[ty + i][tx] = in[(long)(r0 + ty + i) * C + c0 + tx];
    __syncthreads();
#pragma unroll
    for (int i = 0; i < 32; i += 8)
        out[(long)(c0 + ty + i) * R + r0 + tx] = f2bf(tile[tx][ty + i]);
}

// ---------------------------------------------------------------------------
// Kernel 2: transpose fp32 (R x C) -> fp8 (C x R) * WSCALE, with the k-slice
// permutation applied along the output row (R = K dim of GEMM3).
// ---------------------------------------------------------------------------
__global__ __launch_bounds__(256) void k_transpose_fp8p(const float* __restrict__ in,
                                                        uchar* __restrict__ out,
                                                        int R, int C) {
    __shared__ float tile[32][33];
    int c0 = blockIdx.x * 32, r0 = blockIdx.y * 32;
    int tx = threadIdx.x & 31, ty = threadIdx.x >> 5;
#pragma unroll
    for (int i = 0; i < 32; i += 8)
        tile[ty + i][tx] = in[(long)(r0 + ty + i) * C + c0 + tx];
    __syncthreads();
    int k = r0 + tx;
    long dcol = permcol(k);
#pragma unroll
    for (int i = 0; i < 32; i += 8)
        out[(long)(c0 + ty + i) * R + dcol] = f2fp8(tile[tx][ty + i] * WSCALE);
}

// ---------------------------------------------------------------------------
// Kernel 3: GEMM1 with fused A = bf16(cos(x + rx)) staging.
// C[M,N] = cos(X+rx)[M,K] * Bt[N,K]^T + bias[N], bf16 out.
// R5 structure: XOR-swizzled [128][64]-ushort LDS (0 conflicts verified).
// ---------------------------------------------------------------------------
__global__ __launch_bounds__(256, 2)
void k_gemm1(const float* __restrict__ X, const ushort* __restrict__ Bt,
             const float* __restrict__ rx, const float* __restrict__ bias,
             ushort* __restrict__ C, int M, int N, int K) {
    __shared__ __align__(16) ushort lsA[128 * 64];
    __shared__ __align__(16) ushort lsB[128 * 64];
    const int tid = threadIdx.x;
    const int lane = tid & 63;
    const int wave = tid >> 6;
    const int wm = wave & 1, wn = wave >> 1;
    const long m0 = (long)blockIdx.x * 128;
    const long n0 = (long)blockIdx.y * 128;

    const int srow = tid >> 3;
    const int fcol = (tid & 7) * 8;
    const int swc = (tid & 7) ^ (srow & 7);
    const float* gX = X + (m0 + srow) * (long)K + fcol;
    const ushort* gB = Bt + (n0 + srow) * (long)K + fcol;
    ushort* wA = lsA + srow * 64 + swc * 8;
    ushort* wB = lsB + srow * 64 + swc * 8;

    float rxv[8];
#pragma unroll
    for (int j = 0; j < 8; ++j) rxv[j] = rx[fcol + j];

    f32x4 acc[4][4] = {};
    const int rbase = lane & 15;
    const int khalf = lane >> 4;
    const int rswz = lane & 7;

    for (int kt = 0; kt < K; kt += 64) {
        float xv[4][8];
        ushortx8 bv[4];
#pragma unroll
        for (int i = 0; i < 4; ++i) {
            float4 lo = *(const float4*)(gX + kt + (long)(32 * i) * K);
            float4 hi = *(const float4*)(gX + kt + (long)(32 * i) * K + 4);
            xv[i][0] = lo.x; xv[i][1] = lo.y; xv[i][2] = lo.z; xv[i][3] = lo.w;
            xv[i][4] = hi.x; xv[i][5] = hi.y; xv[i][6] = hi.z; xv[i][7] = hi.w;
            bv[i] = *(const ushortx8*)(gB + kt + (long)(32 * i) * K);
        }
        if (kt) __syncthreads();
#pragma unroll
        for (int i = 0; i < 4; ++i) {
            ushortx8 o;
#pragma unroll
            for (int j = 0; j < 8; ++j) o[j] = f2bf(__cosf(xv[i][j] + rxv[j]));
            *(ushortx8*)(wA + i * 2048) = o;
            *(ushortx8*)(wB + i * 2048) = bv[i];
        }
        __syncthreads();
#pragma unroll
        for (int kk = 0; kk < 64; kk += 32) {
            const int ko = (((kk >> 3) + khalf) ^ rswz) * 8;
            bf16x8 af[4], bfr[4];
#pragma unroll
            for (int t = 0; t < 4; ++t) {
                af[t]  = as_bf16x8(*(const ushortx8*)&lsA[(wm * 64 + t * 16 + rbase) * 64 + ko]);
                bfr[t] = as_bf16x8(*(const ushortx8*)&lsB[(wn * 64 + t * 16 + rbase) * 64 + ko]);
            }
#pragma unroll
            for (int tm = 0; tm < 4; ++tm)
#pragma unroll
                for (int tn = 0; tn < 4; ++tn)
                    acc[tm][tn] = __builtin_amdgcn_mfma_f32_16x16x32_bf16(af[tm], bfr[tn], acc[tm][tn], 0, 0, 0);
        }
    }

    const int cr = (lane >> 4) * 4;
    const int cc = lane & 15;
#pragma unroll
    for (int tm = 0; tm < 4; ++tm)
#pragma unroll
        for (int tn = 0; tn < 4; ++tn) {
            long col = n0 + wn * 64 + tn * 16 + cc;
            float bb = bias[col];
#pragma unroll
            for (int j = 0; j < 4; ++j) {
                long row = m0 + wm * 64 + tm * 16 + cr + j;
                C[row * N + col] = f2bf(acc[tm][tn][j] + bb);
            }
        }
}

// ---------------------------------------------------------------------------
// Kernel 4: fp8 GEMM3 with k-slice-permuted global blocks.
// A lane's 4 MFMA operands (kk=0,32,64,96 at its khalf) = logical slices
// 4t+khalf = stored positions khalf*4+t = 2 contiguous 16B chunks ->
// 2x ds_read_b128 per fragment (chunk (khalf*2+h)^(row&7) swizzle, free).
// Staging identical to R5 (16B chunks, xor swizzle, b128 writes).
// ---------------------------------------------------------------------------
__global__ __launch_bounds__(256, 2)
void k_gemm_fp8(const uchar* __restrict__ A, const uchar* __restrict__ Bt,
                const float* __restrict__ bias, ushort* __restrict__ C,
                int M, int N, int K) {
    __shared__ __align__(16) uchar lsA[128 * 128];
    __shared__ __align__(16) uchar lsB[128 * 128];
    const int tid = threadIdx.x;
    const int lane = tid & 63;
    const int wave = tid >> 6;
    const int wm = wave & 1, wn = wave >> 1;
    const long m0 = (long)blockIdx.x * 128;
    const long n0 = (long)blockIdx.y * 128;

    const int srow = tid >> 3;
    const int cg = tid & 7;
    const int swc = cg ^ (srow & 7);
    const uchar* gA = A + (m0 + srow) * (long)K + cg * 16;
    const uchar* gB = Bt + (n0 + srow) * (long)K + cg * 16;
    uchar* wA = lsA + srow * 128 + swc * 16;
    uchar* wB = lsB + srow * 128 + swc * 16;

    f32x4 acc[4][4] = {};
    const int rbase = lane & 15;
    const int khalf = lane >> 4;   // 0..3

    for (int kt = 0; kt < K; kt += 128) {
        ushortx8 av[4], bv[4];
#pragma unroll
        for (int i = 0; i < 4; ++i) {
            av[i] = *(const ushortx8*)(gA + kt + (long)(32 * i) * K);
            bv[i] = *(const ushortx8*)(gB + kt + (long)(32 * i) * K);
        }
        if (kt) __syncthreads();
#pragma unroll
        for (int i = 0; i < 4; ++i) {
            *(ushortx8*)(wA + i * 4096) = av[i];
            *(ushortx8*)(wB + i * 4096) = bv[i];
        }
        __syncthreads();
#pragma unroll
        for (int h = 0; h < 2; ++h) {
            longx2 la[4], lb[4];
#pragma unroll
            for (int f = 0; f < 4; ++f) {
                int rA = wm * 64 + f * 16 + rbase;
                int rB = wn * 64 + f * 16 + rbase;
                la[f] = *(const longx2*)&lsA[rA * 128 + ((((khalf << 1) | h) ^ (rA & 7)) * 16)];
                lb[f] = *(const longx2*)&lsB[rB * 128 + ((((khalf << 1) | h) ^ (rB & 7)) * 16)];
            }
#pragma unroll
            for (int tm = 0; tm < 4; ++tm)
#pragma unroll
                for (int tn = 0; tn < 4; ++tn)
                    acc[tm][tn] = __builtin_amdgcn_mfma_f32_16x16x32_fp8_fp8(la[tm].x, lb[tn].x, acc[tm][tn], 0, 0, 0);
#pragma unroll
            for (int tm = 0; tm < 4; ++tm)
#pragma unroll
                for (int tn = 0; tn < 4; ++tn)
                    acc[tm][tn] = __builtin_amdgcn_mfma_f32_16x16x32_fp8_fp8(la[tm].y, lb[tn].y, acc[tm][tn], 0, 0, 0);
        }
    }

    const int cr = (lane >> 4) * 4;
    const int cc = lane & 15;
#pragma unroll
    for (int tm = 0; tm < 4; ++tm)
#pragma unroll
        for (int tn = 0; tn < 4; ++tn) {
            long col = n0 + wn * 64 + tn * 16 + cc;
            float bb = bias[col];
#pragma unroll
            for (int j = 0; j < 4; ++j) {
                long row = m0 + wm * 64 + tm * 16 + cr + j;
                C[row * N + col] = f2bf(acc[tm][tn][j] * INV_SCALE + bb);
            }
        }
}

// ---------------------------------------------------------------------------
// Kernel 5: LN1: x1(bf16) = LN(x_f32 + attn_bf16); q = cos(x1[:, :8])*cos(ry)
// One wave per row, no barriers.
// ---------------------------------------------------------------------------
__global__ __launch_bounds__(256) void k_ln1(const float* __restrict__ x,
                                             const ushort* __restrict__ y,
                                             const float* __restrict__ g,
                                             const float* __restrict__ b,
                                             ushort* __restrict__ out,
                                             float* __restrict__ qout,
                                             const float* __restrict__ ry) {
    const int lane = threadIdx.x & 63;
    const int wave = threadIdx.x >> 6;
    const long row = (long)blockIdx.x * 4 + wave;
    const float* xr = x + row * E_DIM;
    const ushort* yr = y + row * E_DIM;
    float4 v[3];
    float s = 0.f, ss = 0.f;
#pragma unroll
    for (int i = 0; i < 3; ++i) {
        int c = lane * 4 + i * 256;
        float4 a = *(const float4*)(xr + c);
        ushortx4 d4 = *(const ushortx4*)(yr + c);
        v[i].x = a.x + bf2f(d4[0]); v[i].y = a.y + bf2f(d4[1]);
        v[i].z = a.z + bf2f(d4[2]); v[i].w = a.w + bf2f(d4[3]);
        s  += v[i].x + v[i].y + v[i].z + v[i].w;
        ss += v[i].x * v[i].x + v[i].y * v[i].y + v[i].z * v[i].z + v[i].w * v[i].w;
    }
#pragma unroll
    for (int o = 1; o < 64; o <<= 1) {
        s  += __shfl_xor(s, o);
        ss += __shfl_xor(ss, o);
    }
    const float mu = s * (1.f / E_DIM);
    const float rstd = rsqrtf(ss * (1.f / E_DIM) - mu * mu + 1e-5f);
#pragma unroll
    for (int i = 0; i < 3; ++i) {
        int c = lane * 4 + i * 256;
        float4 gg = *(const float4*)(g + c);
        float4 bb = *(const float4*)(b + c);
        float4 o;
        o.x = (v[i].x - mu) * rstd * gg.x + bb.x;
        o.y = (v[i].y - mu) * rstd * gg.y + bb.y;
        o.z = (v[i].z - mu) * rstd * gg.z + bb.z;
        o.w = (v[i].w - mu) * rstd * gg.w + bb.w;
        ushortx4 o4;
        o4[0] = f2bf(o.x); o4[1] = f2bf(o.y); o4[2] = f2bf(o.z); o4[3] = f2bf(o.w);
        *(ushortx4*)(out + row * E_DIM + c) = o4;
        if (i == 0 && lane < 2) {
            float4 r4 = *(const float4*)(ry + lane * 4);
            float* qo = qout + row * NQ + lane * 4;
            qo[0] = __cosf(o.x) * __cosf(r4.x);
            qo[1] = __cosf(o.y) * __cosf(r4.y);
            qo[2] = __cosf(o.z) * __cosf(r4.z);
            qo[3] = __cosf(o.w) * __cosf(r4.w);
        }
    }
}

// ---------------------------------------------------------------------------
// Kernel 6: LN2: out(f32) = LN(x1_bf16 + ffn_bf16)
// ---------------------------------------------------------------------------
__global__ __launch_bounds__(256) void k_ln2(const ushort* __restrict__ x,
                                             const ushort* __restrict__ y,
                                             const float* __restrict__ g,
                                             const float* __restrict__ b,
                                             float* __restrict__ out) {
    const int lane = threadIdx.x & 63;
    const int wave = threadIdx.x >> 6;
    const long row = (long)blockIdx.x * 4 + wave;
    const ushort* xr = x + row * E_DIM;
    const ushort* yr = y + row * E_DIM;
    float4 v[3];
    float s = 0.f, ss = 0.f;
#pragma unroll
    for (int i = 0; i < 3; ++i) {
        int c = lane * 4 + i * 256;
        ushortx4 a4 = *(const ushortx4*)(xr + c);
        ushortx4 d4 = *(const ushortx4*)(yr + c);
        v[i].x = bf2f(a4[0]) + bf2f(d4[0]); v[i].y = bf2f(a4[1]) + bf2f(d4[1]);
        v[i].z = bf2f(a4[2]) + bf2f(d4[2]); v[i].w = bf2f(a4[3]) + bf2f(d4[3]);
        s  += v[i].x + v[i].y + v[i].z + v[i].w;
        ss += v[i].x * v[i].x + v[i].y * v[i].y + v[i].z * v[i].z + v[i].w * v[i].w;
    }
#pragma unroll
    for (int o = 1; o < 64; o <<= 1) {
        s  += __shfl_xor(s, o);
        ss += __shfl_xor(ss, o);
    }
    const float mu = s * (1.f / E_DIM);
    const float rstd = rsqrtf(ss * (1.f / E_DIM) - mu * mu + 1e-5f);
#pragma unroll
    for (int i = 0; i < 3; ++i) {
        int c = lane * 4 + i * 256;
        float4 gg = *(const float4*)(g + c);
        float4 bb = *(const float4*)(b + c);
        float4 o;
        o.x = (v[i].x - mu) * rstd * gg.x + bb.x;
        o.y = (v[i].y - mu) * rstd * gg.y + bb.y;
        o.z = (v[i].z - mu) * rstd * gg.z + bb.z;
        o.w = (v[i].w - mu) * rstd * gg.w + bb.w;
        *(float4*)(out + row * E_DIM + c) = o;
    }
}

// ---------------------------------------------------------------------------
// Kernel 7: h8[m, pos] = fp8( HSCALE * relu(b1[n] + sum_j q[m,j]*W1[j,n]) )
// where pos is the k-slice-permuted position of logical n.
// ---------------------------------------------------------------------------
__global__ __launch_bounds__(256) void k_ffn1(const float* __restrict__ q,
                                              const float* __restrict__ W1,
                                              const float* __restrict__ b1,
                                              uchar* __restrict__ h) {
    __shared__ float qs[32][NQ];
    const int r0 = blockIdx.x * 32;
    const int tid = threadIdx.x;
    qs[tid >> 3][tid & 7] = q[(long)r0 * NQ + tid];
    __syncthreads();
#pragma unroll
    for (int nb = 0; nb < 3; ++nb) {
        int pp = (nb * 256 + tid) * 4;             // output byte position
        int qpos = (pp >> 3) & 15;
        int n = (pp & ~127) | ((((qpos & 3) << 2) | (qpos >> 2)) << 3) | (pp & 7);
        float4 w[NQ];
#pragma unroll
        for (int j = 0; j < NQ; ++j) w[j] = *(const float4*)(W1 + j * FFN_DIM + n);
        float4 bb = *(const float4*)(b1 + n);
#pragma unroll
        for (int r = 0; r < 32; ++r) {
            float a0 = bb.x, a1 = bb.y, a2 = bb.z, a3 = bb.w;
#pragma unroll
            for (int j = 0; j < NQ; ++j) {
                float qv = qs[r][j];
                a0 += qv * w[j].x; a1 += qv * w[j].y;
                a2 += qv * w[j].z; a3 += qv * w[j].w;
            }
            a0 = fmaxf(a0, 0.f) * HSCALE; a1 = fmaxf(a1, 0.f) * HSCALE;
            a2 = fmaxf(a2, 0.f) * HSCALE; a3 = fmaxf(a3, 0.f) * HSCALE;
            uchar4 o;
            o.x = f2fp8(a0); o.y = f2fp8(a1); o.z = f2fp8(a2); o.w = f2fp8(a3);
            *(uchar4*)(h + (long)(r0 + r) * FFN_DIM + pp) = o;
        }
    }
}

// ---------------------------------------------------------------------------

extern "C" void kernel_launch(void* const* d_in, const int* in_sizes, int n_in,
                              void* d_out, int out_size, void* d_ws, size_t ws_size,
                              hipStream_t stream) {
    const float* x   = (const float*)d_in[0];
    const float* rx  = (const float*)d_in[1];
    const float* ry  = (const float*)d_in[2];
    const float* Wc  = (const float*)d_in[3];
    const float* bc  = (const float*)d_in[4];
    const float* W1  = (const float*)d_in[5];
    const float* b1  = (const float*)d_in[6];
    const float* W2  = (const float*)d_in[7];
    const float* b2  = (const float*)d_in[8];
    const float* g1  = (const float*)d_in[9];
    const float* be1 = (const float*)d_in[10];
    const float* g2  = (const float*)d_in[11];
    const float* be2 = (const float*)d_in[12];
    float* out = (float*)d_out;

    char* ws = (char*)d_ws;
    ushort* wcT  = (ushort*)ws;                 ws += (size_t)E_DIM * E_DIM * 2;      // 1.2 MB
    ushort* attn = (ushort*)ws;                 ws += (size_t)M_ROWS * E_DIM * 2;     // 25 MB (bf16, reused as ffn_out)
    ushort* x1   = (ushort*)ws;                 ws += (size_t)M_ROWS * E_DIM * 2;     // 25 MB (bf16)
    float*  q    = (float*)ws;                  ws += (size_t)M_ROWS * NQ * 4;        // 0.5 MB
    uchar*  w2T8 = (uchar*)ws;                  ws += (size_t)E_DIM * FFN_DIM;        // 2.4 MB
    uchar*  h8   = (uchar*)ws;                  ws += (size_t)M_ROWS * FFN_DIM;       // 50 MB

    // 1. WcT = bf16(Wc^T);  W2T8 = fp8(W2^T * 32) with k-slice permutation
    k_transpose_bf<<<dim3(E_DIM / 32, E_DIM / 32), 256, 0, stream>>>(Wc, wcT, E_DIM, E_DIM);
    k_transpose_fp8p<<<dim3(E_DIM / 32, FFN_DIM / 32), 256, 0, stream>>>(W2, w2T8, FFN_DIM, E_DIM);
    // 2. attn(bf16) = cos(x+rx) @ Wc + bc   (cos fused into staging)
    k_gemm1<<<dim3(M_ROWS / 128, E_DIM / 128), 256, 0, stream>>>(x, wcT, rx, bc, attn, M_ROWS, E_DIM, E_DIM);
    // 3. x1(bf16) = LN(x + attn); q = cos(x1[:, :8]) * cos(ry)
    k_ln1<<<M_ROWS / 4, 256, 0, stream>>>(x, attn, g1, be1, x1, q, ry);
    // 4. h8 = fp8(16 * relu(q @ W1 + b1)), k-slice-permuted blocks
    k_ffn1<<<M_ROWS / 32, 256, 0, stream>>>(q, W1, b1, h8);
    // 5. ffn(bf16) = (h8 @ W2T8)/512 + b2  (reuse attn buffer)
    k_gemm_fp8<<<dim3(M_ROWS / 128, E_DIM / 128), 256, 0, stream>>>(h8, w2T8, b2, attn, M_ROWS, E_DIM, FFN_DIM);
    // 6. out = LN(x1 + ffn)
    k_ln2<<<M_ROWS / 4, 256, 0, stream>>>(x1, attn, g2, be2, out);
}